// Round 1
// baseline (1885.963 us; speedup 1.0000x reference)
//
#include <hip/hip_runtime.h>

typedef unsigned short ushort_t;
typedef __attribute__((ext_vector_type(8))) short bf16x8;
typedef __attribute__((ext_vector_type(4))) float f32x4;

__device__ __forceinline__ float b2f(ushort_t u) {
    return __builtin_bit_cast(float, (unsigned int)u << 16);
}
__device__ __forceinline__ ushort_t f2b_rne(float f) {
    unsigned int u = __builtin_bit_cast(unsigned int, f);
    unsigned int r = u + 0x7FFFu + ((u >> 16) & 1u);
    return (ushort_t)(r >> 16);
}
// bf16-pair (packed in dword) * scalar -> bf16 pair, truncating (bias compensated by caller)
__device__ __forceinline__ unsigned int zmul2(unsigned int w, float s) {
    float lo = __builtin_bit_cast(float, w << 16);
    float hi = __builtin_bit_cast(float, w & 0xFFFF0000u);
    unsigned int plo = __builtin_bit_cast(unsigned int, lo * s);
    unsigned int phi = __builtin_bit_cast(unsigned int, hi * s);
    return (plo >> 16) | (phi & 0xFFFF0000u);
}

// ---- prep: x (B,64,32) f32 -> x0t bf16 [b*32+d][80] (h contiguous, 16-elem zero pad) ----
__global__ void cin_prep_x0t(const float* __restrict__ x, ushort_t* __restrict__ x0t) {
    __shared__ float xs[2048];
    const int b = blockIdx.x, t = threadIdx.x;
    const float4* src = (const float4*)(x + (size_t)b * 2048);
    float4* dst = (float4*)xs;
    dst[t] = src[t];
    dst[t + 256] = src[t + 256];
    __syncthreads();
    for (int task = t; task < 320; task += 256) {
        int d = task / 10;
        int j = task - d * 10;
        unsigned int w[4] = {0u, 0u, 0u, 0u};
        if (j < 8) {
#pragma unroll
            for (int q = 0; q < 4; ++q) {
                ushort_t a = f2b_rne(xs[(j * 8 + 2 * q) * 32 + d]);
                ushort_t c = f2b_rne(xs[(j * 8 + 2 * q + 1) * 32 + d]);
                w[q] = (unsigned int)a | ((unsigned int)c << 16);
            }
        }
        uint4 o; o.x = w[0]; o.y = w[1]; o.z = w[2]; o.w = w[3];
        *(uint4*)(x0t + ((size_t)b * 32 + d) * 80 + j * 8) = o;
    }
}

// ---- prep: K (128,G,64) f32 -> Kp bf16 [g][k][80] ----
__global__ void cin_prep_k(const float* __restrict__ K, ushort_t* __restrict__ Kp, int G) {
    const int g = blockIdx.x, t = threadIdx.x;
    for (int task = t; task < 1280; task += 256) {
        int k = task / 10;
        int j = task - k * 10;
        unsigned int w[4] = {0u, 0u, 0u, 0u};
        if (j < 8) {
            const float* s = K + ((size_t)k * G + g) * 64 + j * 8;
#pragma unroll
            for (int q = 0; q < 4; ++q) {
                ushort_t a = f2b_rne(s[2 * q]);
                ushort_t c = f2b_rne(s[2 * q + 1]);
                w[q] = (unsigned int)a | ((unsigned int)c << 16);
            }
        }
        uint4 o; o.x = w[0]; o.y = w[1]; o.z = w[2]; o.w = w[3];
        *(uint4*)(Kp + ((size_t)g * 128 + k) * 80 + j * 8) = o;
    }
}

// ---- layer kernel: fm[k,n] = relu( sum_g sum_h K[k,g,h]*xi[b,g,d]*x0[b,h,d] + bias[k] )
//      out[b, off+k] += ... (pooled over d);  fm stored bf16 [b][k][d] if STORE_FM.
template <int G, bool XI_FROM_X0, bool STORE_FM>
__launch_bounds__(256, 2)
__global__ void cin_layer(const ushort_t* __restrict__ x0t,  // [B*32][80]
                          const ushort_t* __restrict__ xi,   // [B][G][32] bf16 (prev fm), unused if XI_FROM_X0
                          const ushort_t* __restrict__ Kp,   // [G][128][80]
                          const float* __restrict__ bias,    // [128]
                          ushort_t* __restrict__ fm_out,     // [B][128][32]
                          float* __restrict__ out,           // [B][384]
                          int layer_off) {
    __shared__ ushort_t x0_s[10240];  // [n:128][80]
    __shared__ ushort_t z_s[10240];   // [n:128][80] (col kk=h)
    __shared__ ushort_t k_s[10240];   // [m:128][80]
    const int t = threadIdx.x;
    const int wg = blockIdx.x;
    const int lane = t & 63;
    const int wave = t >> 6;
    const long b0 = (long)wg * 4;

    {  // prologue staging: x0 tile + K(g=0), each 20480B = 1280 uint4
        const uint4* sx = (const uint4*)(x0t + b0 * 32 * 80);
        const uint4* sk = (const uint4*)Kp;
        uint4* dx = (uint4*)x0_s;
        uint4* dk = (uint4*)k_s;
#pragma unroll
        for (int i = 0; i < 5; ++i) {
            dx[t + 256 * i] = sx[t + 256 * i];
            dk[t + 256 * i] = sk[t + 256 * i];
        }
    }

    f32x4 acc[4][4];
#pragma unroll
    for (int a = 0; a < 4; ++a)
#pragma unroll
        for (int bq = 0; bq < 4; ++bq) acc[a][bq] = (f32x4){0.f, 0.f, 0.f, 0.f};

    const int n = t & 127;      // z / x0 row (column of GEMM within tile)
    const int half = t >> 7;    // which 32-h half this thread generates
    const int bl = n >> 5;      // local batch 0..3
    const int d = n & 31;
    const ushort_t* xi_p = XI_FROM_X0 ? (const ushort_t*)nullptr
                                      : (xi + ((b0 + bl) * G) * 32 + d);

    __syncthreads();

    ushort_t xi_cur, xi_nxt = 0;
    if (XI_FROM_X0) xi_cur = x0_s[n * 80 + 0];
    else            xi_cur = xi_p[0];

    uint4 kreg[5];
    const int wave_m = wave >> 1, wave_n = wave & 1;
    const int col = lane & 15, g4 = lane >> 4;

    for (int g = 0; g < G; ++g) {
        // P1: prefetch K(g+1) into regs, xi(g+1)
        if (g + 1 < G) {
            const uint4* sk = (const uint4*)(Kp + (size_t)(g + 1) * 10240);
#pragma unroll
            for (int i = 0; i < 5; ++i) kreg[i] = sk[t + 256 * i];
            if (XI_FROM_X0) xi_nxt = x0_s[n * 80 + (g + 1)];
            else            xi_nxt = xi_p[(size_t)(g + 1) * 32];
        }
        // z-gen: z[n][h] = xi[b,g,d] * x0[b,h,d]  (trunc pack, compensated)
        {
            const float xif = b2f(xi_cur) * 1.0019569f;
            const ushort_t* xrow = x0_s + n * 80 + half * 32;
            ushort_t* zrow = z_s + n * 80 + half * 32;
#pragma unroll
            for (int j = 0; j < 4; ++j) {
                uint4 v = *(const uint4*)(xrow + j * 8);
                uint4 o;
                o.x = zmul2(v.x, xif);
                o.y = zmul2(v.y, xif);
                o.z = zmul2(v.z, xif);
                o.w = zmul2(v.w, xif);
                *(uint4*)(zrow + j * 8) = o;
            }
        }
        __syncthreads();  // B1: z(g) visible, k_s holds K(g)
        // P2: fragment reads + 32 MFMA
#pragma unroll
        for (int ks2 = 0; ks2 < 2; ++ks2) {
            bf16x8 af[4], bfv[4];
#pragma unroll
            for (int mf = 0; mf < 4; ++mf)
                af[mf] = *(const bf16x8*)(k_s + (wave_m * 64 + mf * 16 + col) * 80 + ks2 * 32 + g4 * 8);
#pragma unroll
            for (int nf = 0; nf < 4; ++nf)
                bfv[nf] = *(const bf16x8*)(z_s + (wave_n * 64 + nf * 16 + col) * 80 + ks2 * 32 + g4 * 8);
#pragma unroll
            for (int mf = 0; mf < 4; ++mf)
#pragma unroll
                for (int nf = 0; nf < 4; ++nf)
                    acc[mf][nf] = __builtin_amdgcn_mfma_f32_16x16x32_bf16(af[mf], bfv[nf], acc[mf][nf], 0, 0, 0);
        }
        __syncthreads();  // B2: all frag reads done -> k_s/z_s writable
        // P3: commit K(g+1)
        if (g + 1 < G) {
            uint4* dk = (uint4*)k_s;
#pragma unroll
            for (int i = 0; i < 5; ++i) dk[t + 256 * i] = kreg[i];
            xi_cur = xi_nxt;
        }
    }

    // epilogue: bias + relu, store fm bf16, pooled sum over d -> out
#pragma unroll
    for (int mf = 0; mf < 4; ++mf) {
        const int kk = wave_m * 64 + mf * 16 + g4 * 4;
        const float4 bs = *(const float4*)(bias + kk);
        float pool[2][4] = {{0.f, 0.f, 0.f, 0.f}, {0.f, 0.f, 0.f, 0.f}};
#pragma unroll
        for (int nf = 0; nf < 4; ++nf) {
            const int n_loc = wave_n * 64 + nf * 16 + col;
            const long n_g = (long)wg * 128 + n_loc;
            const long b = n_g >> 5;
            const int dd = (int)(n_g & 31);
#pragma unroll
            for (int r = 0; r < 4; ++r) {
                float v = acc[mf][nf][r] + ((r == 0) ? bs.x : (r == 1) ? bs.y : (r == 2) ? bs.z : bs.w);
                v = fmaxf(v, 0.f);
                if (STORE_FM) fm_out[(b * 128 + kk + r) * 32 + dd] = f2b_rne(v);
                pool[nf >> 1][r] += v;
            }
        }
#pragma unroll
        for (int bi = 0; bi < 2; ++bi) {
#pragma unroll
            for (int r = 0; r < 4; ++r) {
                float s = pool[bi][r];
                s += __shfl_xor(s, 1, 16);
                s += __shfl_xor(s, 2, 16);
                s += __shfl_xor(s, 4, 16);
                s += __shfl_xor(s, 8, 16);
                pool[bi][r] = s;
            }
            if (col == 0) {
                const long b = b0 + wave_n * 2 + bi;
                float4 o;
                o.x = pool[bi][0]; o.y = pool[bi][1]; o.z = pool[bi][2]; o.w = pool[bi][3];
                *(float4*)(out + b * 384 + layer_off + kk) = o;
            }
        }
    }
}

extern "C" void kernel_launch(void* const* d_in, const int* in_sizes, int n_in,
                              void* d_out, int out_size, void* d_ws, size_t ws_size,
                              hipStream_t stream) {
    const float* x  = (const float*)d_in[0];
    const float* k0 = (const float*)d_in[1];
    const float* k1 = (const float*)d_in[2];
    const float* k2 = (const float*)d_in[3];
    const float* b0 = (const float*)d_in[4];
    const float* b1 = (const float*)d_in[5];
    const float* b2 = (const float*)d_in[6];
    float* out = (float*)d_out;
    char* ws = (char*)d_ws;

    // workspace layout (all 256B-aligned); total = 182,714,368 B
    ushort_t* x0t = (ushort_t*)(ws);                   // 8192*32*80*2   = 41,943,040
    ushort_t* Kp0 = (ushort_t*)(ws + 41943040);        // 64*128*80*2    =  1,310,720
    ushort_t* Kp1 = (ushort_t*)(ws + 43253760);        // 128*128*80*2   =  2,621,440
    ushort_t* Kp2 = (ushort_t*)(ws + 45875200);        // 128*128*80*2   =  2,621,440
    ushort_t* fm0 = (ushort_t*)(ws + 48496640);        // 8192*128*32*2  = 67,108,864
    ushort_t* fm1 = (ushort_t*)(ws + 115605504);       // 8192*128*32*2  = 67,108,864

    cin_prep_x0t<<<8192, 256, 0, stream>>>(x, x0t);
    cin_prep_k<<<64, 256, 0, stream>>>(k0, Kp0, 64);
    cin_prep_k<<<128, 256, 0, stream>>>(k1, Kp1, 128);
    cin_prep_k<<<128, 256, 0, stream>>>(k2, Kp2, 128);

    cin_layer<64, true, true><<<2048, 256, 0, stream>>>(x0t, (const ushort_t*)nullptr, Kp0, b0, fm0, out, 0);
    cin_layer<128, false, true><<<2048, 256, 0, stream>>>(x0t, fm0, Kp1, b1, fm1, out, 128);
    cin_layer<128, false, false><<<2048, 256, 0, stream>>>(x0t, fm1, Kp2, b2, (ushort_t*)nullptr, out, 256);
}

// Round 2
// 1204.526 us; speedup vs baseline: 1.5657x; 1.5657x over previous
//
#include <hip/hip_runtime.h>

typedef unsigned short ushort_t;
typedef unsigned int u32;
typedef __attribute__((ext_vector_type(8))) short bf16x8;
typedef __attribute__((ext_vector_type(4))) float f32x4;
typedef __attribute__((ext_vector_type(4))) u32 u32x4;

__device__ __forceinline__ float b2f(ushort_t u) {
    return __builtin_bit_cast(float, (u32)u << 16);
}
__device__ __forceinline__ ushort_t f2b_rne(float f) {
    u32 u = __builtin_bit_cast(u32, f);
    u32 r = u + 0x7FFFu + ((u >> 16) & 1u);
    return (ushort_t)(r >> 16);
}
// pack hi16(p0), hi16(p1) -> one dword (low=p0) via v_perm (truncating)
__device__ __forceinline__ u32 pack_trunc(float p0, float p1) {
    return __builtin_amdgcn_perm(__builtin_bit_cast(u32, p1),
                                 __builtin_bit_cast(u32, p0), 0x07060302u);
}
__device__ __forceinline__ void gl_lds16(const ushort_t* g, ushort_t* l) {
    __builtin_amdgcn_global_load_lds(
        (const __attribute__((address_space(1))) u32*)g,
        (__attribute__((address_space(3))) u32*)l, 16, 0, 0);
}

// ---- prep: x (B,64,32) f32 -> x0bf bf16 [n=(b*32+d)][64 h] (RNE) ----
__global__ void cin_prep_x0bf(const float* __restrict__ x, ushort_t* __restrict__ x0bf) {
    __shared__ float xs[64 * 33];
    const int b = blockIdx.x, t = threadIdx.x;
    const float4* src = (const float4*)(x + (size_t)b * 2048);
#pragma unroll
    for (int i = 0; i < 2; ++i) {
        float4 f = src[t + 256 * i];
        int e = (t + 256 * i) * 4;
        int h = e >> 5, d = e & 31;
        xs[h * 33 + d]     = f.x;
        xs[h * 33 + d + 1] = f.y;
        xs[h * 33 + d + 2] = f.z;
        xs[h * 33 + d + 3] = f.w;
    }
    __syncthreads();
    const int d = t >> 3, j8 = t & 7;
    u32 w[4];
#pragma unroll
    for (int q = 0; q < 4; ++q) {
        int h0 = j8 * 8 + 2 * q;
        w[q] = (u32)f2b_rne(xs[h0 * 33 + d]) | ((u32)f2b_rne(xs[(h0 + 1) * 33 + d]) << 16);
    }
    uint4 o; o.x = w[0]; o.y = w[1]; o.z = w[2]; o.w = w[3];
    *(uint4*)(x0bf + ((size_t)b * 32 + d) * 64 + j8 * 8) = o;
}

// ---- prep: K (128,G,64) f32 -> Kp bf16 [g][k][64] with XOR swizzle baked in:
//      element h of row k stored at ushort index h ^ ((k&7)<<3) ----
__global__ void cin_prep_k2(const float* __restrict__ K, ushort_t* __restrict__ Kp, int G) {
    const int g = blockIdx.x, t = threadIdx.x;
    const int k = t >> 1, j0 = (t & 1) * 16;  // dword col base (32 dwords/row)
    const float* s = K + ((size_t)k * G + g) * 64 + j0 * 2;
    u32* dst = (u32*)(Kp + (size_t)g * 8192 + k * 64);
    const int swc = k & 7;  // chunk-level xor (16B chunks)
#pragma unroll
    for (int c = 0; c < 4; ++c) {
        u32 w[4];
#pragma unroll
        for (int q = 0; q < 4; ++q) {
            int e = (c * 4 + q) * 2;
            w[q] = (u32)f2b_rne(s[e]) | ((u32)f2b_rne(s[e + 1]) << 16);
        }
        uint4 o; o.x = w[0]; o.y = w[1]; o.z = w[2]; o.w = w[3];
        *(uint4*)(dst + (((j0 >> 2) + c) ^ swc) * 4) = o;
    }
}

// ---- layer: fm[k,n] = relu( sum_g sum_h K[k,g,h]*xi[n,g]*x0[n,h] + bias[k] )
// x0 base held in registers (f32); B-fragment built in-register per g;
// K double-buffered in LDS via global_load_lds; xi tile in padded LDS.
template <int G, bool STORE_FM>
__launch_bounds__(256, 2)
__global__ void cin_layer2(const ushort_t* __restrict__ x0bf,   // [262144][64]
                           const ushort_t* __restrict__ xi_src, // rows [n][G] bf16
                           const ushort_t* __restrict__ Kp,     // [G][128][64] swizzled
                           const float* __restrict__ bias,      // [128]
                           ushort_t* __restrict__ fm_out,       // [262144][128] (transposed)
                           float* __restrict__ out,             // [B][384]
                           int layer_off) {
    constexpr int XI_STRIDE = G + 8;  // dword-stride ≡ 4 (mod 32) -> 2-way (free)
    __shared__ ushort_t k_lds[2][8192];          // 2 x 16 KB, swizzled rows [128][64]
    __shared__ ushort_t xi_lds[128 * XI_STRIDE];

    const int t = threadIdx.x;
    const int wg = blockIdx.x;
    const int lane = t & 63;
    const int wave = t >> 6;
    const int wm = wave >> 1, wn = wave & 1;
    const int col = lane & 15, g4 = lane >> 4;
    const int swz = (col & 7) << 3;  // A-frag read swizzle (ushort units)

    // ---- prologue: stage xi tile (reg->padded LDS), issue K(0) gload_lds, load x0 base ----
    {
        constexpr int CPR = G / 8;        // uint4 chunks per row
        constexpr int TOT = 128 * CPR;
        const size_t n0 = (size_t)wg * 128;
#pragma unroll
        for (int i = 0; i < TOT / 256; ++i) {
            int c = t + 256 * i;
            int row = c / CPR, sub = c % CPR;
            u32x4 v = *(const u32x4*)(xi_src + (n0 + row) * G + sub * 8);
            *(u32x4*)(xi_lds + row * XI_STRIDE + sub * 8) = v;
        }
    }
    {
        const ushort_t* src = Kp + (size_t)t * 8;
        ushort_t* dst = k_lds[0] + t * 8;
#pragma unroll
        for (int i = 0; i < 4; ++i) gl_lds16(src + i * 2048, dst + i * 2048);
    }
    float xb[4][16];  // x0 base, f32: [nf][ks2*8 + jj]
#pragma unroll
    for (int nf = 0; nf < 4; ++nf) {
        const size_t n_g = (size_t)wg * 128 + wn * 64 + nf * 16 + col;
#pragma unroll
        for (int ks2 = 0; ks2 < 2; ++ks2) {
            u32x4 v = *(const u32x4*)(x0bf + n_g * 64 + ks2 * 32 + g4 * 8);
#pragma unroll
            for (int q = 0; q < 4; ++q) {
                xb[nf][ks2 * 8 + 2 * q]     = __builtin_bit_cast(float, v[q] << 16);
                xb[nf][ks2 * 8 + 2 * q + 1] = __builtin_bit_cast(float, v[q] & 0xFFFF0000u);
            }
        }
    }

    f32x4 acc[4][4];
#pragma unroll
    for (int a = 0; a < 4; ++a)
#pragma unroll
        for (int b = 0; b < 4; ++b) acc[a][b] = (f32x4){0.f, 0.f, 0.f, 0.f};

    __syncthreads();  // drains gload_lds (vmcnt0) + xi ds_writes

    // ---- main loop: one barrier per g ----
    for (int g = 0; g < G; ++g) {
        const int cur = g & 1;
        if (g + 1 < G) {  // prefetch K(g+1) into other buffer
            const ushort_t* src = Kp + (size_t)(g + 1) * 8192 + (size_t)t * 8;
            ushort_t* dst = k_lds[cur ^ 1] + t * 8;
#pragma unroll
            for (int i = 0; i < 4; ++i) gl_lds16(src + i * 2048, dst + i * 2048);
        }
        // xi for this g (broadcast across g4 lanes; compensation folded in)
        float xif[4];
#pragma unroll
        for (int nf = 0; nf < 4; ++nf)
            xif[nf] = b2f(xi_lds[(wn * 64 + nf * 16 + col) * XI_STRIDE + g]) * 1.0019569f;
        // B fragments in-register: 2 mul + 1 perm per dword
        bf16x8 bw[4][2];
#pragma unroll
        for (int nf = 0; nf < 4; ++nf)
#pragma unroll
            for (int ks2 = 0; ks2 < 2; ++ks2) {
                u32x4 wv;
#pragma unroll
                for (int q = 0; q < 4; ++q) {
                    float p0 = xb[nf][ks2 * 8 + 2 * q] * xif[nf];
                    float p1 = xb[nf][ks2 * 8 + 2 * q + 1] * xif[nf];
                    wv[q] = pack_trunc(p0, p1);
                }
                bw[nf][ks2] = __builtin_bit_cast(bf16x8, wv);
            }
        // A fragments (swizzled read) + 32 MFMA
#pragma unroll
        for (int ks2 = 0; ks2 < 2; ++ks2) {
            bf16x8 af[4];
#pragma unroll
            for (int mf = 0; mf < 4; ++mf) {
                const int row = wm * 64 + mf * 16 + col;
                af[mf] = *(const bf16x8*)(k_lds[cur] + row * 64 + ((ks2 * 32 + g4 * 8) ^ swz));
            }
#pragma unroll
            for (int mf = 0; mf < 4; ++mf)
#pragma unroll
                for (int nf = 0; nf < 4; ++nf)
                    acc[mf][nf] = __builtin_amdgcn_mfma_f32_16x16x32_bf16(
                        af[mf], bw[nf][ks2], acc[mf][nf], 0, 0, 0);
        }
        __syncthreads();  // waits K(g+1) arrival + all reads of k_lds[cur] done
    }

    // ---- epilogue: bias+relu, fm_t store, pooled d-sum -> out ----
#pragma unroll
    for (int mf = 0; mf < 4; ++mf) {
        const int kk = wm * 64 + mf * 16 + g4 * 4;
        const float4 bs = *(const float4*)(bias + kk);
        float pool[2][4] = {{0.f, 0.f, 0.f, 0.f}, {0.f, 0.f, 0.f, 0.f}};
#pragma unroll
        for (int nf = 0; nf < 4; ++nf) {
            const size_t n_g = (size_t)wg * 128 + wn * 64 + nf * 16 + col;
            float v[4];
#pragma unroll
            for (int r = 0; r < 4; ++r) {
                float vv = acc[mf][nf][r] + ((r == 0) ? bs.x : (r == 1) ? bs.y : (r == 2) ? bs.z : bs.w);
                vv = fmaxf(vv, 0.f);
                v[r] = vv;
                pool[nf >> 1][r] += vv;
            }
            if (STORE_FM) {
                uint2 ww;
                ww.x = (u32)f2b_rne(v[0]) | ((u32)f2b_rne(v[1]) << 16);
                ww.y = (u32)f2b_rne(v[2]) | ((u32)f2b_rne(v[3]) << 16);
                *(uint2*)(fm_out + n_g * 128 + kk) = ww;
            }
        }
#pragma unroll
        for (int bi = 0; bi < 2; ++bi) {
#pragma unroll
            for (int r = 0; r < 4; ++r) {
                float s = pool[bi][r];
                s += __shfl_xor(s, 1, 16);
                s += __shfl_xor(s, 2, 16);
                s += __shfl_xor(s, 4, 16);
                s += __shfl_xor(s, 8, 16);
                pool[bi][r] = s;
            }
            if (col == 0) {
                const long b = (long)wg * 4 + wn * 2 + bi;
                float4 o;
                o.x = pool[bi][0]; o.y = pool[bi][1]; o.z = pool[bi][2]; o.w = pool[bi][3];
                *(float4*)(out + b * 384 + layer_off + kk) = o;
            }
        }
    }
}

extern "C" void kernel_launch(void* const* d_in, const int* in_sizes, int n_in,
                              void* d_out, int out_size, void* d_ws, size_t ws_size,
                              hipStream_t stream) {
    const float* x  = (const float*)d_in[0];
    const float* k0 = (const float*)d_in[1];
    const float* k1 = (const float*)d_in[2];
    const float* k2 = (const float*)d_in[3];
    const float* bb0 = (const float*)d_in[4];
    const float* bb1 = (const float*)d_in[5];
    const float* bb2 = (const float*)d_in[6];
    float* out = (float*)d_out;
    char* ws = (char*)d_ws;

    // workspace layout; total = 173,015,040 B (round-1 used 182.7 MB OK)
    ushort_t* x0bf = (ushort_t*)(ws);                 // 262144*64*2  = 33,554,432
    ushort_t* Kp0  = (ushort_t*)(ws + 33554432);      // 64*128*64*2  =  1,048,576
    ushort_t* Kp1  = (ushort_t*)(ws + 34603008);      // 128*128*64*2 =  2,097,152
    ushort_t* Kp2  = (ushort_t*)(ws + 36700160);      // 128*128*64*2 =  2,097,152
    ushort_t* fm0  = (ushort_t*)(ws + 38797312);      // 262144*128*2 = 67,108,864
    ushort_t* fm1  = (ushort_t*)(ws + 105906176);     // 262144*128*2 = 67,108,864

    cin_prep_x0bf<<<8192, 256, 0, stream>>>(x, x0bf);
    cin_prep_k2<<<64, 256, 0, stream>>>(k0, Kp0, 64);
    cin_prep_k2<<<128, 256, 0, stream>>>(k1, Kp1, 128);
    cin_prep_k2<<<128, 256, 0, stream>>>(k2, Kp2, 128);

    cin_layer2<64, true><<<2048, 256, 0, stream>>>(x0bf, x0bf, Kp0, bb0, fm0, out, 0);
    cin_layer2<128, true><<<2048, 256, 0, stream>>>(x0bf, fm0, Kp1, bb1, fm1, out, 128);
    cin_layer2<128, false><<<2048, 256, 0, stream>>>(x0bf, fm1, Kp2, bb2, (ushort_t*)nullptr, out, 256);
}